// Round 3
// baseline (73694.379 us; speedup 1.0000x reference)
//
#include <hip/hip_runtime.h>
#include <math.h>

// Problem constants: B=128, L=512, D_IN=512, D_H=1024, D_OUT=256
#define B_   128
#define L_   512
#define DIN  512
#define DH   1024
#define DOUT 256

#define NBLK 256
#define NTHR 256
#define MT   16              // m-tile rows per block  (8 m-tiles)
#define NT   32              // n-tile cols per block  (32 n-tiles)
#define KSL  8               // k-slices across threads (32 n-lanes x 8 slices)
#define KREC (DH / KSL)      // 128 W_rec elems per thread
#define KIN  (DIN / KSL)     // 64  W_in  elems per thread

// Persistent fused RNN kernel.
// Block bid: m-tile = bid&7 (XCD-friendly: one m-tile per XCD), n-tile = bid>>3.
// Thread tid: n-lane = tid&31, k-slice = tid>>5.
// Per step l (1..511):  h_new = tanh(X[:,l,:]*W_in1^T + (l>=2 ? h*W_rec1^T : 0) + b_in1)
// Weights held in registers for the whole 510-step loop; h exchanged through
// global memory with agent-scope (coherent) loads/stores + grid barrier.
__global__ __launch_bounds__(NTHR, 1) void rnn_persist(
    const float* __restrict__ X, const float* __restrict__ W_in1,
    const float* __restrict__ b_in1, const float* __restrict__ W_rec1,
    const float* __restrict__ W_out, const float* __restrict__ b_out,
    float* __restrict__ hA, float* __restrict__ hB,
    unsigned* __restrict__ bar, float* __restrict__ Y) {
  __shared__ __align__(16) float Hs[MT * DH];        // 64 KB
  __shared__ __align__(16) float Xs[MT * DIN];       // 32 KB
  __shared__ __align__(16) float Red[KSL * MT * NT]; // 16 KB

  const int tid = (int)threadIdx.x;
  const int bid = (int)blockIdx.x;
  const int m0 = (bid & 7) * MT;
  const int n0 = (bid >> 3) * NT;
  const int nl = tid & 31;
  const int ks = tid >> 5;
  const int ng = n0 + nl;

  // ---- preload this thread's weight slices into registers (once) ----
  float wrec[KREC], win[KIN];
  {
    const float* wr = W_rec1 + (size_t)ng * DH + ks * KREC;
#pragma unroll
    for (int j = 0; j < KREC / 4; ++j) {
      float4 v = *(const float4*)(wr + j * 4);
      wrec[j * 4 + 0] = v.x; wrec[j * 4 + 1] = v.y;
      wrec[j * 4 + 2] = v.z; wrec[j * 4 + 3] = v.w;
    }
    const float* wi = W_in1 + (size_t)ng * DIN + ks * KIN;
#pragma unroll
    for (int j = 0; j < KIN / 4; ++j) {
      float4 v = *(const float4*)(wi + j * 4);
      win[j * 4 + 0] = v.x; win[j * 4 + 1] = v.y;
      win[j * 4 + 2] = v.z; win[j * 4 + 3] = v.w;
    }
  }
  // reduce-phase constants (each thread finalizes 2 adjacent outputs)
  const int o  = tid << 1;
  const int mo = o >> 5;        // 0..15
  const int no = o & 31;        // even
  const float bi0 = b_in1[n0 + no], bi1 = b_in1[n0 + no + 1];

  unsigned phase = 0;

  for (int l = 1; l < L_; ++l) {
    float* hn       = (l & 1) ? hA : hB;
    const float* hp = (l & 1) ? hB : hA;

    // issue coherent h-tile loads early; they land under the proj compute
    float hreg[64];
    if (l > 1) {
      const float* hsrc = hp + (size_t)m0 * DH;
#pragma unroll
      for (int i = 0; i < 64; ++i)
        hreg[i] = __hip_atomic_load(hsrc + tid + i * NTHR, __ATOMIC_RELAXED,
                                    __HIP_MEMORY_SCOPE_AGENT);
    }
    // stage X[:, l, :] tile: MT*DIN = 8192 floats = 256 thr * 8 chunks * 4
    // (round-2 bug: only 2 chunks were staged -> 3/4 of Xs stale)
#pragma unroll
    for (int c = 0; c < 8; ++c) {
      const int e = (tid + c * NTHR) * 4;   // element in [0, MT*DIN)
      const int m = e >> 9, k = e & 511;
      float4 v = *(const float4*)&X[((size_t)(m0 + m) * L_ + l) * DIN + k];
      *(float4*)&Xs[m * DIN + k] = v;
    }
    __syncthreads();

    // ---- proj partial: acc[m] = X-tile row . win-slice ----
    float acc[MT];
#pragma unroll
    for (int m = 0; m < MT; ++m) {
      const float* xr = &Xs[m * DIN + ks * KIN];
      float s0 = 0, s1 = 0, s2 = 0, s3 = 0;
#pragma unroll
      for (int k4 = 0; k4 < KIN / 4; ++k4) {
        float4 x4 = *(const float4*)(xr + k4 * 4);
        s0 += x4.x * win[k4 * 4 + 0];
        s1 += x4.y * win[k4 * 4 + 1];
        s2 += x4.z * win[k4 * 4 + 2];
        s3 += x4.w * win[k4 * 4 + 3];
      }
      acc[m] = (s0 + s1) + (s2 + s3);
    }

    if (l > 1) {
      // publish staged h to LDS, then recurrent partial
#pragma unroll
      for (int i = 0; i < 64; ++i) Hs[tid + i * NTHR] = hreg[i];
      __syncthreads();
#pragma unroll
      for (int m = 0; m < MT; ++m) {
        const float* hr = &Hs[m * DH + ks * KREC];
        float s0 = 0, s1 = 0, s2 = 0, s3 = 0;
#pragma unroll
        for (int k4 = 0; k4 < KREC / 4; ++k4) {
          float4 h4 = *(const float4*)(hr + k4 * 4);
          s0 += h4.x * wrec[k4 * 4 + 0];
          s1 += h4.y * wrec[k4 * 4 + 1];
          s2 += h4.z * wrec[k4 * 4 + 2];
          s3 += h4.w * wrec[k4 * 4 + 3];
        }
        acc[m] += (s0 + s1) + (s2 + s3);
      }
    }

    // ---- reduce across k-slices, tanh, store h_new ----
#pragma unroll
    for (int m = 0; m < MT; ++m) Red[(ks * MT + m) * NT + nl] = acc[m];
    __syncthreads();
    float s0 = 0, s1 = 0;
#pragma unroll
    for (int q = 0; q < KSL; ++q) {
      float2 r = *(const float2*)&Red[(q * MT + mo) * NT + no];
      s0 += r.x; s1 += r.y;
    }
    const float v0 = tanhf(s0 + bi0);
    const float v1 = tanhf(s1 + bi1);
    float* hw = hn + (size_t)(m0 + mo) * DH + n0 + no;
    __hip_atomic_store(hw,     v0, __ATOMIC_RELAXED, __HIP_MEMORY_SCOPE_AGENT);
    __hip_atomic_store(hw + 1, v1, __ATOMIC_RELAXED, __HIP_MEMORY_SCOPE_AGENT);

    // ---- grid barrier (all 256 blocks co-resident: 112 KB LDS -> 1/CU) ----
    __threadfence();
    __syncthreads();
    ++phase;
    if (tid == 0) {
      __hip_atomic_fetch_add(bar, 1u, __ATOMIC_ACQ_REL, __HIP_MEMORY_SCOPE_AGENT);
      const unsigned tgt = phase * NBLK;
      while (__hip_atomic_load(bar, __ATOMIC_ACQUIRE, __HIP_MEMORY_SCOPE_AGENT) < tgt)
        __builtin_amdgcn_s_sleep(8);
    }
    __syncthreads();
  }

  // ---- output layer: Y = tanh(h_final @ W_out^T + b_out); h_final in hA ----
  if (bid < 64) {
    const int n0o = (bid >> 3) * NT;   // 8 out n-tiles
    const int ngo = n0o + nl;
    const float* hsrc = hA + (size_t)m0 * DH;
    float hreg[64];
#pragma unroll
    for (int i = 0; i < 64; ++i)
      hreg[i] = __hip_atomic_load(hsrc + tid + i * NTHR, __ATOMIC_RELAXED,
                                  __HIP_MEMORY_SCOPE_AGENT);
    float wo[KREC];
    const float* wr = W_out + (size_t)ngo * DH + ks * KREC;
#pragma unroll
    for (int j = 0; j < KREC / 4; ++j) {
      float4 v = *(const float4*)(wr + j * 4);
      wo[j * 4 + 0] = v.x; wo[j * 4 + 1] = v.y;
      wo[j * 4 + 2] = v.z; wo[j * 4 + 3] = v.w;
    }
#pragma unroll
    for (int i = 0; i < 64; ++i) Hs[tid + i * NTHR] = hreg[i];
    __syncthreads();
    float acc[MT];
#pragma unroll
    for (int m = 0; m < MT; ++m) {
      const float* hr = &Hs[m * DH + ks * KREC];
      float s0 = 0, s1 = 0, s2 = 0, s3 = 0;
#pragma unroll
      for (int k4 = 0; k4 < KREC / 4; ++k4) {
        float4 h4 = *(const float4*)(hr + k4 * 4);
        s0 += h4.x * wo[k4 * 4 + 0];
        s1 += h4.y * wo[k4 * 4 + 1];
        s2 += h4.z * wo[k4 * 4 + 2];
        s3 += h4.w * wo[k4 * 4 + 3];
      }
      acc[m] = (s0 + s1) + (s2 + s3);
    }
#pragma unroll
    for (int m = 0; m < MT; ++m) Red[(ks * MT + m) * NT + nl] = acc[m];
    __syncthreads();
    float s0 = 0, s1 = 0;
#pragma unroll
    for (int q = 0; q < KSL; ++q) {
      float2 r = *(const float2*)&Red[(q * MT + mo) * NT + no];
      s0 += r.x; s1 += r.y;
    }
    const int nc = n0o + no;
    Y[(size_t)(m0 + mo) * DOUT + nc]     = tanhf(s0 + b_out[nc]);
    Y[(size_t)(m0 + mo) * DOUT + nc + 1] = tanhf(s1 + b_out[nc + 1]);
  }
}

extern "C" void kernel_launch(void* const* d_in, const int* in_sizes, int n_in,
                              void* d_out, int out_size, void* d_ws, size_t ws_size,
                              hipStream_t stream) {
  const float* X      = (const float*)d_in[0];
  const float* W_in1  = (const float*)d_in[1];
  const float* b_in1  = (const float*)d_in[2];
  const float* W_rec1 = (const float*)d_in[3];
  // d_in[4..6] = W_in2/b_in2/W_rec2 : dead code w.r.t. Y
  const float* W_out  = (const float*)d_in[7];
  const float* b_out  = (const float*)d_in[8];
  float* out = (float*)d_out;

  // ws layout: [0,4096): barrier counter; then hA, hB (512 KB each)
  unsigned* bar = (unsigned*)d_ws;
  float* hA = (float*)((char*)d_ws + 4096);
  float* hB = hA + (size_t)B_ * DH;

  hipMemsetAsync(d_ws, 0, 4096, stream);  // reset barrier each launch (replay-safe)
  rnn_persist<<<NBLK, NTHR, 0, stream>>>(X, W_in1, b_in1, W_rec1, W_out, b_out,
                                         hA, hB, bar, out);
}

// Round 5
// 26627.969 us; speedup vs baseline: 2.7676x; 2.7676x over previous
//
#include <hip/hip_runtime.h>
#include <math.h>

// Problem constants: B=128, L=512, D_IN=512, D_H=1024, D_OUT=256
#define B_   128
#define L_   512
#define DIN  512
#define DH   1024
#define DOUT 256

#define NBLK 256
#define NTHR 512

typedef float f32x4 __attribute__((ext_vector_type(4)));

__device__ __forceinline__ float hload(const float* p) {
  return __hip_atomic_load(p, __ATOMIC_RELAXED, __HIP_MEMORY_SCOPE_AGENT);
}
__device__ __forceinline__ void hstore(float* p, float v) {
  __hip_atomic_store(p, v, __ATOMIC_RELAXED, __HIP_MEMORY_SCOPE_AGENT);
}

// Persistent fused RNN.
// Grid 256 x 512, 128 KB LDS -> exactly 1 block/CU (co-resident; proven in R3).
// Block: m-tile = (bid&7)*16 rows, n-tile = (bid>>3)*32 cols.
// Thread: cg = lane&7 (cols cg*4..+3), kssub = lane>>3, ks = wavei*8+kssub (64 k-slices).
// Step l: h_new = tanh(X_l W_in1^T + (l>=2 ? h W_rec1^T : 0) + b_in1).
// W slices live in registers (96 f32/thread, ~235 VGPR total -> no spill at 256 cap).
// h exchanged through global memory with agent-scope atomics; per-m-group barrier
// (32 blocks: the writers of m-tile g are exactly its readers).
__global__ __launch_bounds__(NTHR, 2) void rnn_persist(
    const float* __restrict__ X, const float* __restrict__ W_in1,
    const float* __restrict__ b_in1, const float* __restrict__ W_rec1,
    const float* __restrict__ W_out, const float* __restrict__ b_out,
    float* __restrict__ hA, float* __restrict__ hB,
    unsigned* __restrict__ bar, float* __restrict__ Y) {
  __shared__ __align__(16) float Hs[16 * 1024];  // 64 KB, XOR-swizzled cols
  __shared__ __align__(16) float Xs[16 * 512];   // 32 KB, XOR-swizzled cols
  __shared__ __align__(16) float Red[16 * 512];  // 32 KB [prt][m*32+n]

  const int tid   = (int)threadIdx.x;
  const int bid   = (int)blockIdx.x;
  const int m0    = (bid & 7) * 16;
  const int n0    = (bid >> 3) * 32;
  const int lane  = tid & 63;
  const int wavei = tid >> 6;
  const int cg    = lane & 7;
  const int kssub = lane >> 3;
  const int ks    = wavei * 8 + kssub;

  // ---- register-resident weight slices (loaded once) ----
  float wrec[4][16], win[4][8];
#pragma unroll
  for (int nj = 0; nj < 4; ++nj) {
    const float* wr = W_rec1 + (size_t)(n0 + cg * 4 + nj) * DH + ks * 16;
#pragma unroll
    for (int q = 0; q < 4; ++q) {
      const f32x4 v = *(const f32x4*)(wr + q * 4);
      wrec[nj][q * 4 + 0] = v[0]; wrec[nj][q * 4 + 1] = v[1];
      wrec[nj][q * 4 + 2] = v[2]; wrec[nj][q * 4 + 3] = v[3];
    }
    const float* wi = W_in1 + (size_t)(n0 + cg * 4 + nj) * DIN + ks * 8;
    const f32x4 a = *(const f32x4*)(wi);
    const f32x4 b = *(const f32x4*)(wi + 4);
    win[nj][0] = a[0]; win[nj][1] = a[1]; win[nj][2] = a[2]; win[nj][3] = a[3];
    win[nj][4] = b[0]; win[nj][5] = b[1]; win[nj][6] = b[2]; win[nj][7] = b[3];
  }
  // swizzled LDS column offsets (bank-conflict-free broadcast reads)
  const int swz = (ks & 7) << 2;
  const int xq0 = (ks * 8) ^ swz;
  const int xq1 = (ks * 8 + 4) ^ swz;
  int rp[4];
#pragma unroll
  for (int j4 = 0; j4 < 4; ++j4) rp[j4] = (ks * 16 + j4 * 4) ^ swz;

  const int mo = tid >> 5, no = tid & 31;   // this thread's finalized output
  const float bi = b_in1[n0 + no];
  const int prt = wavei * 2 + (kssub >> 2); // 16 reduction partials

  unsigned phase = 0;
#pragma unroll 1
  for (int l = 1; l < L_; ++l) {
    const float* hp = (l & 1) ? hB : hA;
    float* hn       = (l & 1) ? hA : hB;

    // issue coherent h loads first; compiler defers the wait to first use
    // (after proj), so their latency hides under the X stage + proj compute
    float hreg[32];
    if (l > 1) {
      const float* hsrc = hp + (size_t)m0 * DH;  // this block's 16 rows (64 KB)
#pragma unroll
      for (int i = 0; i < 32; ++i) hreg[i] = hload(hsrc + tid + i * NTHR);
    }
    // stage X[:, l, :] tile: 8192 floats = 512 thr x 4 x f32x4, swizzled cols
#pragma unroll
    for (int p = 0; p < 4; ++p) {
      const int e = tid * 4 + p * 2048;
      const int m = e >> 9, k = e & 511;
      const f32x4 v = *(const f32x4*)&X[((size_t)(m0 + m) * L_ + l) * DIN + k];
      *(f32x4*)&Xs[m * 512 + (k ^ (((k >> 3) & 7) << 2))] = v;
    }
    __syncthreads();

    // ---- proj partials ----
    __align__(16) float acc[16][4];
#pragma unroll
    for (int m = 0; m < 16; ++m)
#pragma unroll
      for (int nj = 0; nj < 4; ++nj) acc[m][nj] = 0.f;
#pragma unroll
    for (int m = 0; m < 16; ++m) {
      const f32x4 a = *(const f32x4*)&Xs[m * 512 + xq0];
      const f32x4 b = *(const f32x4*)&Xs[m * 512 + xq1];
#pragma unroll
      for (int nj = 0; nj < 4; ++nj)
#pragma unroll
        for (int c = 0; c < 4; ++c) {
          acc[m][nj] += a[c] * win[nj][c];
          acc[m][nj] += b[c] * win[nj][4 + c];
        }
    }

    if (l > 1) {
      // publish h to LDS (swizzled scatter), then recurrent partials
#pragma unroll
      for (int i = 0; i < 32; ++i) {
        const int idx = tid + i * NTHR;
        const int row = idx >> 10, col = idx & 1023;
        Hs[row * 1024 + (col ^ (((col >> 4) & 7) << 2))] = hreg[i];
      }
      __syncthreads();
#pragma unroll
      for (int m = 0; m < 16; ++m)
#pragma unroll
        for (int j4 = 0; j4 < 4; ++j4) {
          const f32x4 h4 = *(const f32x4*)&Hs[m * 1024 + rp[j4]];
#pragma unroll
          for (int nj = 0; nj < 4; ++nj)
#pragma unroll
            for (int c = 0; c < 4; ++c) acc[m][nj] += h4[c] * wrec[nj][j4 * 4 + c];
        }
    }

    // ---- reduce: in-wave butterfly over kssub bits 0,1; Red for the rest ----
#pragma unroll
    for (int m = 0; m < 16; ++m)
#pragma unroll
      for (int nj = 0; nj < 4; ++nj) {
        float v = acc[m][nj];
        v += __shfl_xor(v, 8);
        v += __shfl_xor(v, 16);
        acc[m][nj] = v;
      }
    if ((kssub & 3) == 0) {
#pragma unroll
      for (int m = 0; m < 16; ++m)
        *(f32x4*)&Red[(prt * 16 + m) * 32 + cg * 4] = *(const f32x4*)&acc[m][0];
    }
    __syncthreads();

    // ---- finalize 1 output/thread: sum 16 partials, bias, tanh, coherent store ----
    {
      float s = 0.f;
#pragma unroll
      for (int p2 = 0; p2 < 16; ++p2) s += Red[(p2 * 16 + mo) * 32 + no];
      hstore(hn + (size_t)(m0 + mo) * DH + n0 + no, tanhf(s + bi));
    }
    // ---- per-m-group barrier (32 blocks with this bid&7) ----
    __threadfence();
    __syncthreads();
    ++phase;
    if (tid == 0) {
      unsigned* ctr = bar + (size_t)(bid & 7) * 32;  // 128 B apart
      __hip_atomic_fetch_add(ctr, 1u, __ATOMIC_ACQ_REL, __HIP_MEMORY_SCOPE_AGENT);
      const unsigned tgt = phase * 32u;
      while (__hip_atomic_load(ctr, __ATOMIC_ACQUIRE, __HIP_MEMORY_SCOPE_AGENT) < tgt)
        __builtin_amdgcn_s_sleep(1);
    }
    __syncthreads();
  }

  // ---- output layer: Y = tanh(h_final @ W_out^T + b_out); h_final = hA ----
  if (bid < 64) {
    const int n0o = (bid >> 3) * 32;
    float wout[4][16];
#pragma unroll
    for (int nj = 0; nj < 4; ++nj) {
      const float* wr = W_out + (size_t)(n0o + cg * 4 + nj) * DH + ks * 16;
#pragma unroll
      for (int q = 0; q < 4; ++q) {
        const f32x4 v = *(const f32x4*)(wr + q * 4);
        wout[nj][q * 4 + 0] = v[0]; wout[nj][q * 4 + 1] = v[1];
        wout[nj][q * 4 + 2] = v[2]; wout[nj][q * 4 + 3] = v[3];
      }
    }
    const float bo = b_out[n0o + no];
    const float* hsrc = hA + (size_t)m0 * DH;
    float hreg[32];
#pragma unroll
    for (int i = 0; i < 32; ++i) hreg[i] = hload(hsrc + tid + i * NTHR);
#pragma unroll
    for (int i = 0; i < 32; ++i) {
      const int idx = tid + i * NTHR;
      const int row = idx >> 10, col = idx & 1023;
      Hs[row * 1024 + (col ^ (((col >> 4) & 7) << 2))] = hreg[i];
    }
    __syncthreads();
    __align__(16) float acc[16][4];
#pragma unroll
    for (int m = 0; m < 16; ++m)
#pragma unroll
      for (int nj = 0; nj < 4; ++nj) acc[m][nj] = 0.f;
#pragma unroll
    for (int m = 0; m < 16; ++m)
#pragma unroll
      for (int j4 = 0; j4 < 4; ++j4) {
        const f32x4 h4 = *(const f32x4*)&Hs[m * 1024 + rp[j4]];
#pragma unroll
        for (int nj = 0; nj < 4; ++nj)
#pragma unroll
          for (int c = 0; c < 4; ++c) acc[m][nj] += h4[c] * wout[nj][j4 * 4 + c];
      }
#pragma unroll
    for (int m = 0; m < 16; ++m)
#pragma unroll
      for (int nj = 0; nj < 4; ++nj) {
        float v = acc[m][nj];
        v += __shfl_xor(v, 8);
        v += __shfl_xor(v, 16);
        acc[m][nj] = v;
      }
    if ((kssub & 3) == 0) {
#pragma unroll
      for (int m = 0; m < 16; ++m)
        *(f32x4*)&Red[(prt * 16 + m) * 32 + cg * 4] = *(const f32x4*)&acc[m][0];
    }
    __syncthreads();
    float s = 0.f;
#pragma unroll
    for (int p2 = 0; p2 < 16; ++p2) s += Red[(p2 * 16 + mo) * 32 + no];
    Y[(size_t)(m0 + mo) * DOUT + n0o + no] = tanhf(s + bo);
  }
}

extern "C" void kernel_launch(void* const* d_in, const int* in_sizes, int n_in,
                              void* d_out, int out_size, void* d_ws, size_t ws_size,
                              hipStream_t stream) {
  const float* X      = (const float*)d_in[0];
  const float* W_in1  = (const float*)d_in[1];
  const float* b_in1  = (const float*)d_in[2];
  const float* W_rec1 = (const float*)d_in[3];
  // d_in[4..6] = W_in2/b_in2/W_rec2 : dead code w.r.t. Y
  const float* W_out  = (const float*)d_in[7];
  const float* b_out  = (const float*)d_in[8];
  float* out = (float*)d_out;

  // ws layout: [0,4096): 8 group-barrier counters (128 B apart); then hA, hB
  unsigned* bar = (unsigned*)d_ws;
  float* hA = (float*)((char*)d_ws + 4096);
  float* hB = hA + (size_t)B_ * DH;

  hipMemsetAsync(d_ws, 0, 4096, stream);  // reset barriers each launch (replay-safe)
  rnn_persist<<<NBLK, NTHR, 0, stream>>>(X, W_in1, b_in1, W_rec1, W_out, b_out,
                                         hA, hB, bar, out);
}